// Round 10
// baseline (605.936 us; speedup 1.0000x reference)
//
#include <hip/hip_runtime.h>
#include <stdint.h>

#define H     1024
#define S     2048
#define SEQE  2048
#define NHEAD 16
#define HD    64
#define INNER 4096
#define EPSLN 1e-5f
#define LOG2E 1.44269504089f
#define SCALE2 (0.125f * LOG2E)

typedef __attribute__((ext_vector_type(8))) short short8;
typedef __attribute__((ext_vector_type(4))) float floatx4;

__device__ __forceinline__ float b2f(unsigned short u){
  union { unsigned int i; float f; } v; v.i = ((unsigned int)u) << 16; return v.f;
}
__device__ __forceinline__ unsigned short f2b(float f){
  union { float f; unsigned int i; } v; v.f = f;
  unsigned int x = v.i;
  unsigned int r = (x + 0x7FFFu + ((x >> 16) & 1u)) >> 16;
  return (unsigned short)r;
}
__device__ __forceinline__ float fexp2(float x){ return __builtin_amdgcn_exp2f(x); }
__device__ __forceinline__ float gelu_tanh(float x){
  float x3 = x*x*x;
  float t = tanhf(0.7978845608028654f*(x + 0.044715f*x3));
  return 0.5f*x*(1.0f+t);
}

// async global->LDS, 16B per lane; LDS dest = wave-uniform base + lane*16
__device__ __forceinline__ void gld16(const unsigned short* g, unsigned short* l){
  __builtin_amdgcn_global_load_lds(
      (const __attribute__((address_space(1))) unsigned int*)g,
      (__attribute__((address_space(3))) unsigned int*)l,
      16, 0, 0);
}

// ---------------- dtype sniff ----------------
__global__ __launch_bounds__(256) void k_sniff(
    const unsigned short* __restrict__ p, int* __restrict__ flag){
  __shared__ int any;
  if (threadIdx.x == 0) any = 0;
  __syncthreads();
  int bad = 0;
  for (int i = threadIdx.x; i < 8192; i += 256){
    float v = b2f(p[i]);
    if (!(fabsf(v) < 1e6f)) bad = 1;
  }
  if (bad) any = 1;
  __syncthreads();
  if (threadIdx.x == 0) flag[0] = any;
}

// ---------------- fused weight transposes ----------------
struct PrepT {
  const void* src[7];
  unsigned short* dst[7];
  int R[7], C[7];
  int pre[8];
};
__global__ __launch_bounds__(256) void k_prep_t(PrepT d, const int* __restrict__ flag){
  __shared__ unsigned short t[32][33];
  int b = blockIdx.x;
  int m = 0;
  while (b >= d.pre[m+1]) m++;
  int ti = b - d.pre[m];
  int R = d.R[m], C = d.C[m];
  int tx = threadIdx.x & 31, ty = threadIdx.x >> 5;
  int tilesx = C >> 5;
  int bc = (ti % tilesx) << 5, br = (ti / tilesx) << 5;
  const float* sf = (const float*)d.src[m];
  const unsigned short* sb = (const unsigned short*)d.src[m];
  unsigned short* dst = d.dst[m];
  int fl = flag[0];
  #pragma unroll
  for (int i = 0; i < 4; i++){
    size_t idx = (size_t)(br + ty + i*8) * C + bc + tx;
    t[ty + i*8][tx] = fl ? f2b(sf[idx]) : sb[idx];
  }
  __syncthreads();
  #pragma unroll
  for (int i = 0; i < 4; i++)
    dst[(size_t)(bc + ty + i*8) * R + br + tx] = t[tx][ty + i*8];
}

// ---------------- fused converts ----------------
struct SmallCvt {
  const void* src[16];
  unsigned short* dst[16];
  int n[16];
};
__global__ __launch_bounds__(256) void k_prep_c(
    const void* __restrict__ enc, unsigned short* __restrict__ enc_c,
    const void* __restrict__ hsv, float* __restrict__ hidden,
    SmallCvt sc, const int* __restrict__ flag){
  int b = blockIdx.x, tid = threadIdx.x;
  int fl = flag[0];
  if (b < 8192){
    int i = b*256 + tid;
    enc_c[i] = fl ? f2b(((const float*)enc)[i]) : ((const unsigned short*)enc)[i];
  } else if (b < 16384){
    int i = (b - 8192)*256 + tid;
    hidden[i] = fl ? ((const float*)hsv)[i] : b2f(((const unsigned short*)hsv)[i]);
  } else {
    int t = b - 16384;
    const float* sf = (const float*)sc.src[t];
    const unsigned short* sb = (const unsigned short*)sc.src[t];
    unsigned short* d = sc.dst[t];
    for (int i = tid; i < sc.n[t]; i += 256){
      float vv = fl ? sf[i] : b2f(sb[i]);
      if (t == 13) vv *= LOG2E;     // scorer pre-scaled to exp2 domain
      d[i] = f2b(vv);
    }
  }
}

// ---------------- LayerNorm ----------------
__global__ __launch_bounds__(256) void k_layernorm(
    const float* __restrict__ x,
    const unsigned short* __restrict__ g, const unsigned short* __restrict__ bb,
    unsigned short* __restrict__ y){
  __shared__ float scratch[4];
  int row = blockIdx.x, tid = threadIdx.x;
  float v[4];
  #pragma unroll
  for (int i=0;i<4;i++) v[i] = x[(size_t)row*H + tid + i*256];
  float s = v[0]+v[1]+v[2]+v[3];
  for (int o=32;o;o>>=1) s += __shfl_xor(s,o,64);
  int wid = tid>>6, lane = tid&63;
  if (lane==0) scratch[wid]=s;
  __syncthreads();
  float mu = (scratch[0]+scratch[1]+scratch[2]+scratch[3]) * (1.0f/H);
  __syncthreads();
  float q = 0.f;
  #pragma unroll
  for (int i=0;i<4;i++){ float d=v[i]-mu; q += d*d; }
  for (int o=32;o;o>>=1) q += __shfl_xor(q,o,64);
  if (lane==0) scratch[wid]=q;
  __syncthreads();
  float var = (scratch[0]+scratch[1]+scratch[2]+scratch[3]) * (1.0f/H);
  float rstd = rsqrtf(var + EPSLN);
  #pragma unroll
  for (int i=0;i<4;i++){
    int idx = tid + i*256;
    float o = (v[i]-mu)*rstd*b2f(g[idx]) + b2f(bb[idx]);
    y[(size_t)row*H + idx] = f2b(o);
  }
}

// ---------------- bf16 MFMA GEMM, 64x128 tile, BK=64, dbuf async staging ----------------
__global__ __launch_bounds__(256) void k_gemm64(
    const unsigned short* __restrict__ A, const unsigned short* __restrict__ BT,
    const unsigned short* __restrict__ bias,
    unsigned short* __restrict__ outb, float* __restrict__ resid,
    int M, int N, int K, int mode, const int* __restrict__ flag,
    int vcol0, unsigned short* __restrict__ vtout)
{
  __shared__ __align__(16) unsigned short As[2][64*64];
  __shared__ __align__(16) unsigned short Bs[2][128*64];
  int tid = threadIdx.x;
  int bm0 = blockIdx.y * 64, bn0 = blockIdx.x * 128;
  int wid = tid >> 6, lane = tid & 63;
  int wm = (wid & 1) * 32, wn = (wid >> 1) * 64;
  floatx4 acc[2][4] = {};

  const unsigned short* gp[6];
  int lofs[6];
  int aseg[6];
  int lrow = lane >> 3, lchunk = (lane & 7) ^ lrow;
  #pragma unroll
  for (int t = 0; t < 6; t++){
    int seg = wid * 6 + t;
    if (seg < 8){
      gp[t] = A + (size_t)(bm0 + seg*8 + lrow) * K + lchunk*8;
      lofs[t] = seg * 512;
      aseg[t] = 1;
    } else {
      int s = seg - 8;
      gp[t] = BT + (size_t)(bn0 + s*8 + lrow) * K + lchunk*8;
      lofs[t] = s * 512;
      aseg[t] = 0;
    }
  }

  #pragma unroll
  for (int t = 0; t < 6; t++)
    gld16(gp[t], (aseg[t] ? As[0] : Bs[0]) + lofs[t]);

  int mrow = lane & 15, quad = lane >> 4;
  int ib = 0;
  for (int kt = 0; kt < K; kt += 64, ib ^= 1){
    __syncthreads();
    if (kt + 64 < K){
      #pragma unroll
      for (int t = 0; t < 6; t++)
        gld16(gp[t] + kt + 64, (aseg[t] ? As[ib^1] : Bs[ib^1]) + lofs[t]);
    }
    const unsigned short* Ac = As[ib];
    const unsigned short* Bc = Bs[ib];
    #pragma unroll
    for (int k2 = 0; k2 < 2; k2++){
      short8 af[2], bf[4];
      #pragma unroll
      for (int i = 0; i < 2; i++){
        int r = wm + i*16 + mrow;
        int slot = (k2*4 + quad) ^ (r & 7);
        af[i] = *(const short8*)&Ac[r*64 + slot*8];
      }
      #pragma unroll
      for (int j = 0; j < 4; j++){
        int r = wn + j*16 + mrow;
        int slot = (k2*4 + quad) ^ (r & 7);
        bf[j] = *(const short8*)&Bc[r*64 + slot*8];
      }
      #pragma unroll
      for (int i = 0; i < 2; i++){
        #pragma unroll
        for (int j = 0; j < 4; j++){
          acc[i][j] = __builtin_amdgcn_mfma_f32_16x16x32_bf16(af[i], bf[j], acc[i][j], 0,0,0);
        }
      }
    }
  }

  int colb = mrow, rowb = quad * 4;
  #pragma unroll
  for (int i=0;i<2;i++){
    #pragma unroll
    for (int j=0;j<4;j++){
      int col = bn0 + wn + j*16 + colb;
      float bv = b2f(bias[col]);
      int row0 = bm0 + wm + i*16 + rowb;
      if (mode == 4 && col >= vcol0){
        ushort4 uv;
        uv.x = f2b(acc[i][j][0] + bv);
        uv.y = f2b(acc[i][j][1] + bv);
        uv.z = f2b(acc[i][j][2] + bv);
        uv.w = f2b(acc[i][j][3] + bv);
        *(ushort4*)(vtout + (size_t)(col - vcol0)*M + row0) = uv;
      } else {
        #pragma unroll
        for (int rr=0;rr<4;rr++){
          int row = row0 + rr;
          float v = acc[i][j][rr] + bv;
          size_t off = (size_t)row*N + col;
          if      (mode == 0 || mode == 4){ outb[off] = f2b(v); }
          else if (mode == 1){ outb[off] = f2b(gelu_tanh(v)); }
          else               { resid[off] += v; }     // mode 2 (single writer)
        }
      }
    }
  }
}

// ---------------- bf16 MFMA GEMM, 64x64 tile, optional split-K via grid.z ------------
// mode 0: out = bf16(v+bias)        [grid.z == 1]
// mode 2: resid[off] += v+bias      [grid.z == 1, single writer]
// mode 5: part[z*M*N + off] = v (+bias if z==0)   [disjoint partials, no atomics]
__global__ __launch_bounds__(256) void k_gemm64s(
    const unsigned short* __restrict__ A, const unsigned short* __restrict__ BT,
    const unsigned short* __restrict__ bias,
    unsigned short* __restrict__ outb, float* __restrict__ resid,
    float* __restrict__ part,
    int M, int N, int K, int klen, int mode)
{
  __shared__ __align__(16) unsigned short As[2][64*64];
  __shared__ __align__(16) unsigned short Bs[2][64*64];
  int tid = threadIdx.x;
  int bm0 = blockIdx.y * 64, bn0 = blockIdx.x * 64;
  int k0 = blockIdx.z * klen;
  int wid = tid >> 6, lane = tid & 63;
  int wm = wid * 16;
  floatx4 acc[4] = {};

  const unsigned short* gp[4];
  int lofs[4];
  int aseg[4];
  int lrow = lane >> 3, lchunk = (lane & 7) ^ lrow;
  #pragma unroll
  for (int t = 0; t < 4; t++){
    int seg = wid * 4 + t;
    if (seg < 8){
      gp[t] = A + (size_t)(bm0 + seg*8 + lrow) * K + k0 + lchunk*8;
      lofs[t] = seg * 512;
      aseg[t] = 1;
    } else {
      int s = seg - 8;
      gp[t] = BT + (size_t)(bn0 + s*8 + lrow) * K + k0 + lchunk*8;
      lofs[t] = s * 512;
      aseg[t] = 0;
    }
  }

  #pragma unroll
  for (int t = 0; t < 4; t++)
    gld16(gp[t], (aseg[t] ? As[0] : Bs[0]) + lofs[t]);

  int mrow = lane & 15, quad = lane >> 4;
  int ib = 0;
  for (int kt = 0; kt < klen; kt += 64, ib ^= 1){
    __syncthreads();
    if (kt + 64 < klen){
      #pragma unroll
      for (int t = 0; t < 4; t++)
        gld16(gp[t] + kt + 64, (aseg[t] ? As[ib^1] : Bs[ib^1]) + lofs[t]);
    }
    const unsigned short* Ac = As[ib];
    const unsigned short* Bc = Bs[ib];
    #pragma unroll
    for (int k2 = 0; k2 < 2; k2++){
      short8 af, bf[4];
      {
        int r = wm + mrow;
        int slot = (k2*4 + quad) ^ (r & 7);
        af = *(const short8*)&Ac[r*64 + slot*8];
      }
      #pragma unroll
      for (int j = 0; j < 4; j++){
        int r = j*16 + mrow;
        int slot = (k2*4 + quad) ^ (r & 7);
        bf[j] = *(const short8*)&Bc[r*64 + slot*8];
      }
      #pragma unroll
      for (int j = 0; j < 4; j++)
        acc[j] = __builtin_amdgcn_mfma_f32_16x16x32_bf16(af, bf[j], acc[j], 0,0,0);
    }
  }

  int colb = mrow, rowb = quad * 4;
  #pragma unroll
  for (int j=0;j<4;j++){
    int col = bn0 + j*16 + colb;
    float bv = (blockIdx.z == 0) ? b2f(bias[col]) : 0.f;
    int row0 = bm0 + wm + rowb;
    #pragma unroll
    for (int rr=0;rr<4;rr++){
      int row = row0 + rr;
      float v = acc[j][rr] + bv;
      size_t off = (size_t)row*N + col;
      if      (mode == 0) outb[off] = f2b(v);
      else if (mode == 2) resid[off] += v;
      else                part[(size_t)blockIdx.z*M*N + off] = v;
    }
  }
}

// ---------------- finalize: out = p0 + p1 + hidden (flag dtype) ----------------
__global__ __launch_bounds__(256) void k_finalize(
    const float* __restrict__ p0, const float* __restrict__ p1,
    const float* __restrict__ hidden, unsigned short* __restrict__ out,
    const int* __restrict__ flag){
  int i = blockIdx.x * 256 + threadIdx.x;
  float v = p0[i] + p1[i] + hidden[i];
  if (flag[0]) ((float*)out)[i] = v;
  else         out[i] = f2b(v);
}

// ---------------- split-K flash attention, barrier-free K-loop --------------------
// K and V^T fragments are read DIRECTLY from global (16B contiguous per lane) —
// no LDS staging, no __syncthreads in the loop. P round-trips per-wave LDS only.
template<int CA, int SCOR>
__global__ __launch_bounds__(256) void k_flash3(
    const unsigned short* __restrict__ qb, int qstride,
    const unsigned short* __restrict__ kb, int kstride,
    const unsigned short* __restrict__ vt,
    const unsigned short* __restrict__ scorer,
    unsigned short* __restrict__ obuf, float* __restrict__ mlbuf, int TOTS)
{
  int t = blockIdx.x, h = blockIdx.y, sp = blockIdx.z;
  int klmax0 = 64*t + 64 + CA; if (klmax0 > S) klmax0 = S;
  int nch = (klmax0 + 63) >> 6;
  int nsp = (nch + 7) >> 3;
  if (sp >= nsp) return;
  int base = 0;
  for (int i = 0; i < t; i++){
    int km = 64*i + 64 + CA; if (km > S) km = S;
    base += (((km + 63) >> 6) + 7) >> 3;
  }
  int pidx = h*TOTS + base + sp;
  int c0 = sp*8, c1 = c0 + 8; if (c1 > nch) c1 = nch;

  __shared__ __align__(16) unsigned short Ps[4][16*72];   // per-wave private
  int tid = threadIdx.x;
  int q0 = t*64;
  int w = tid >> 6, lane = tid & 63;
  int cn = lane & 15, quad = lane >> 4, kq = quad * 8;
  unsigned short* Pw = Ps[w];

  const unsigned short* qrow = qb + (size_t)(q0 + w*16 + cn) * qstride + h*HD;
  short8 qf0 = *(const short8*)(qrow + kq);
  short8 qf1 = *(const short8*)(qrow + kq + 32);
  // per-lane fragment base pointers (all 16B-aligned)
  const unsigned short* kfrag = kb + (size_t)cn * kstride + h*HD + kq;
  const unsigned short* vfrag = vt + (size_t)(h*HD + cn) * S + kq;

  floatx4 oacc[4] = {};
  float l_lane[4] = {0,0,0,0};
  float m_w = -1.0e38f;
  int qmr = q0 + w*16 + quad*4;

  for (int ci = c0; ci < c1; ci++){
    int kc = ci * 64;
    const unsigned short* kcp = kfrag + (size_t)kc * kstride;
    floatx4 sv[4] = {};
    #pragma unroll
    for (int t4=0;t4<4;t4++){
      const unsigned short* kp = kcp + (size_t)(t4*16) * kstride;
      short8 b0 = *(const short8*)kp;
      short8 b1 = *(const short8*)(kp + 32);
      sv[t4] = __builtin_amdgcn_mfma_f32_16x16x32_bf16(qf0, b0, sv[t4], 0,0,0);
      sv[t4] = __builtin_amdgcn_mfma_f32_16x16x32_bf16(qf1, b1, sv[t4], 0,0,0);
    }
    float sc4[4];
    if (SCOR){
      #pragma unroll
      for (int t4=0;t4<4;t4++) sc4[t4] = b2f(scorer[kc + t4*16 + cn]);
    }

    float vals[16];
    float lmax = -1.0e38f;
    if (kc + 63 > q0 + w*16 + CA){          // wave-uniform: diagonal (masked) chunk
      #pragma unroll
      for (int t4=0;t4<4;t4++){
        #pragma unroll
        for (int r=0;r<4;r++){
          float s = sv[t4][r] * SCALE2;
          if (SCOR) s += sc4[t4];
          int kn = kc + t4*16 + cn;
          s = (kn <= qmr + r + CA) ? s : -1.0e38f;
          vals[t4*4+r] = s;
          lmax = fmaxf(lmax, s);
        }
      }
    } else {
      #pragma unroll
      for (int t4=0;t4<4;t4++){
        #pragma unroll
        for (int r=0;r<4;r++){
          float s = sv[t4][r] * SCALE2;
          if (SCOR) s += sc4[t4];
          vals[t4*4+r] = s;
          lmax = fmaxf(lmax, s);
        }
      }
    }
    lmax = fmaxf(lmax, __shfl_xor(lmax,1,64));
    lmax = fmaxf(lmax, __shfl_xor(lmax,2,64));
    lmax = fmaxf(lmax, __shfl_xor(lmax,4,64));
    lmax = fmaxf(lmax, __shfl_xor(lmax,8,64));
    float mnew = fmaxf(m_w, lmax);
    float al = fexp2(m_w - mnew);
    m_w = mnew;
    #pragma unroll
    for (int r=0;r<4;r++) l_lane[r] *= al;
    #pragma unroll
    for (int t2=0;t2<4;t2++){
      #pragma unroll
      for (int r=0;r<4;r++) oacc[t2][r] *= al;
    }
    #pragma unroll
    for (int t4=0;t4<4;t4++){
      #pragma unroll
      for (int r=0;r<4;r++){
        float e = fexp2(vals[t4*4+r] - m_w);
        l_lane[r] += e;
        Pw[(quad*4+r)*72 + t4*16 + cn] = f2b(e);
      }
    }
    short8 pf0 = *(const short8*)&Pw[cn*72 + kq];      // lgkmcnt only (per-wave)
    short8 pf1 = *(const short8*)&Pw[cn*72 + kq + 32];
    const unsigned short* vcp = vfrag + kc;
    #pragma unroll
    for (int t2=0;t2<4;t2++){
      const unsigned short* vp = vcp + (size_t)(t2*16) * S;
      short8 v0 = *(const short8*)vp;
      short8 v1 = *(const short8*)(vp + 32);
      oacc[t2] = __builtin_amdgcn_mfma_f32_16x16x32_bf16(pf0, v0, oacc[t2], 0,0,0);
      oacc[t2] = __builtin_amdgcn_mfma_f32_16x16x32_bf16(pf1, v1, oacc[t2], 0,0,0);
    }
  }

  float lrow[4];
  #pragma unroll
  for (int r=0;r<4;r++){
    float l = l_lane[r];
    l += __shfl_xor(l,1,64); l += __shfl_xor(l,2,64);
    l += __shfl_xor(l,4,64); l += __shfl_xor(l,8,64);
    lrow[r] = l;
  }
  size_t ob = (size_t)pidx*4096 + (size_t)(w*16 + quad*4)*64;
  #pragma unroll
  for (int t2=0;t2<4;t2++){
    #pragma unroll
    for (int r=0;r<4;r++)
      obuf[ob + r*64 + t2*16 + cn] = f2b(oacc[t2][r]);
  }
  if (cn == 0){
    #pragma unroll
    for (int r=0;r<4;r++){
      int row64 = w*16 + quad*4 + r;
      mlbuf[((size_t)pidx*64 + row64)*2]   = m_w;
      mlbuf[((size_t)pidx*64 + row64)*2+1] = lrow[r];
    }
  }
}

// ---------------- split-K combine ----------------
template<int CA>
__global__ __launch_bounds__(256) void k_comb(
    const unsigned short* __restrict__ obuf, const float* __restrict__ mlbuf,
    unsigned short* __restrict__ out, int TOTS)
{
  int h = blockIdx.y;
  int row = blockIdx.x*16 + (threadIdx.x >> 4);
  int d0 = (threadIdx.x & 15) * 4;
  int t = row >> 6;
  int klmax0 = 64*t + 64 + CA; if (klmax0 > S) klmax0 = S;
  int nch = (klmax0 + 63) >> 6;
  int nsp = (nch + 7) >> 3;
  int base = 0;
  for (int i = 0; i < t; i++){
    int km = 64*i + 64 + CA; if (km > S) km = S;
    base += (((km + 63) >> 6) + 7) >> 3;
  }
  int row64 = row & 63;
  float mp[4], lp[4];
  float M = -1.0e38f;
  for (int p = 0; p < nsp; p++){
    int pi = h*TOTS + base + p;
    mp[p] = mlbuf[((size_t)pi*64 + row64)*2];
    lp[p] = mlbuf[((size_t)pi*64 + row64)*2+1];
    M = fmaxf(M, mp[p]);
  }
  float L = 0.f;
  float o0=0.f,o1=0.f,o2=0.f,o3=0.f;
  for (int p = 0; p < nsp; p++){
    int pi = h*TOTS + base + p;
    float wgt = fexp2(mp[p] - M);
    L += lp[p]*wgt;
    const unsigned short* op = obuf + (size_t)pi*4096 + row64*64 + d0;
    o0 += b2f(op[0])*wgt; o1 += b2f(op[1])*wgt;
    o2 += b2f(op[2])*wgt; o3 += b2f(op[3])*wgt;
  }
  float inv = 1.0f / L;
  size_t oo = (size_t)row*H + h*HD + d0;
  out[oo]   = f2b(o0*inv); out[oo+1] = f2b(o1*inv);
  out[oo+2] = f2b(o2*inv); out[oo+3] = f2b(o3*inv);
}

extern "C" void kernel_launch(void* const* d_in, const int* in_sizes, int n_in,
                              void* d_out, int out_size, void* d_ws, size_t ws_size,
                              hipStream_t stream)
{
  const void* hs          = d_in[0];
  const void* enc         = d_in[1];
  const void* scorer      = d_in[2];
  const void* ln1_g       = d_in[3];
  const void* ln1_b       = d_in[4];
  const void* c_attn_w    = d_in[5];
  const void* c_attn_b    = d_in[6];
  const void* attn_proj_w = d_in[7];
  const void* attn_proj_b = d_in[8];
  const void* lnx_g       = d_in[9];
  const void* lnx_b       = d_in[10];
  const void* q_attn_w    = d_in[11];
  const void* q_attn_b    = d_in[12];
  const void* x_kv_w      = d_in[13];
  const void* x_kv_b      = d_in[14];
  const void* x_proj_w    = d_in[15];
  const void* x_proj_b    = d_in[16];
  const void* ln2_g       = d_in[17];
  const void* ln2_b       = d_in[18];
  const void* fc_w        = d_in[19];
  const void* fc_b        = d_in[20];
  const void* mlp_proj_w  = d_in[21];
  const void* mlp_proj_b  = d_in[22];
  unsigned short* out = (unsigned short*)d_out;

  char* ws = (char*)d_ws; size_t off = 0;
  auto alloc = [&](size_t bytes)->void*{
    void* p = ws + off; off += (bytes + 255) & ~(size_t)255; return p;
  };
  unsigned short* wT_cattn = (unsigned short*)alloc((size_t)3072*1024*2);
  unsigned short* wT_aproj = (unsigned short*)alloc((size_t)1024*1024*2);
  unsigned short* wT_qattn = (unsigned short*)alloc((size_t)1024*1024*2);
  unsigned short* wT_xkv   = (unsigned short*)alloc((size_t)2048*1024*2);
  unsigned short* wT_xproj = (unsigned short*)alloc((size_t)1024*1024*2);
  unsigned short* wT_fc    = (unsigned short*)alloc((size_t)4096*1024*2);
  unsigned short* wT_mlp   = (unsigned short*)alloc((size_t)1024*4096*2);
  unsigned short* enc_c    = (unsigned short*)alloc((size_t)SEQE*H*2);
  unsigned short* canon    = (unsigned short*)alloc((size_t)32768*2);
  unsigned short* xln      = (unsigned short*)alloc((size_t)S*H*2);
  unsigned short* qkv      = (unsigned short*)alloc((size_t)S*3*H*2);
  unsigned short* attnout  = (unsigned short*)alloc((size_t)S*H*2);
  unsigned short* q2       = (unsigned short*)alloc((size_t)S*H*2);
  unsigned short* kvbuf    = (unsigned short*)alloc((size_t)SEQE*2*H*2);   // 8 MB
  unsigned short* vt_self  = (unsigned short*)alloc((size_t)H*S*2);        // 4 MB
  unsigned short* vt_cross = (unsigned short*)alloc((size_t)H*SEQE*2);     // 4 MB
  unsigned short* fcbuf    = (unsigned short*)alloc((size_t)S*INNER*2);
  float*          hidden   = (float*)alloc((size_t)S*H*4);
  int*            flag     = (int*)alloc(256);

  // flash partials aliased into fcbuf (fcbuf dead until MLP phase)
  unsigned short* obuf  = fcbuf;
  float*          mlbuf = (float*)(fcbuf + (size_t)16*83*4096);
  // mlp split-K partials: kvbuf+vt_self+vt_cross = exactly 16 MB contiguous, dead in MLP phase
  float* mlp_part = (float*)kvbuf;

  unsigned short* p = canon;
  auto carve = [&](int n)->unsigned short*{ unsigned short* q = p; p += n; return q; };
  unsigned short* c_ln1g = carve(1024); unsigned short* c_ln1b = carve(1024);
  unsigned short* c_catb = carve(3072); unsigned short* c_aprb = carve(1024);
  unsigned short* c_lnxg = carve(1024); unsigned short* c_lnxb = carve(1024);
  unsigned short* c_qatb = carve(1024); unsigned short* c_xkvb = carve(2048);
  unsigned short* c_xprb = carve(1024); unsigned short* c_ln2g = carve(1024);
  unsigned short* c_ln2b = carve(1024); unsigned short* c_fcb  = carve(4096);
  unsigned short* c_mlpb = carve(1024); unsigned short* c_scor = carve(2048);

  k_sniff<<<1, 256, 0, stream>>>((const unsigned short*)hs, flag);

  PrepT pt{};
  const void* tsrc[7] = {c_attn_w, attn_proj_w, q_attn_w, x_kv_w, x_proj_w, fc_w, mlp_proj_w};
  unsigned short* tdst[7] = {wT_cattn, wT_aproj, wT_qattn, wT_xkv, wT_xproj, wT_fc, wT_mlp};
  int tR[7] = {1024,1024,1024,1024,1024,1024,4096};
  int tC[7] = {3072,1024,1024,2048,1024,4096,1024};
  int acc_t = 0;
  for (int i=0;i<7;i++){
    pt.src[i]=tsrc[i]; pt.dst[i]=tdst[i]; pt.R[i]=tR[i]; pt.C[i]=tC[i];
    pt.pre[i]=acc_t; acc_t += (tC[i]>>5)*(tR[i]>>5);
  }
  pt.pre[7]=acc_t;
  k_prep_t<<<acc_t, 256, 0, stream>>>(pt, flag);

  SmallCvt sc{};
  const void* ssrc[14] = {ln1_g, ln1_b, c_attn_b, attn_proj_b, lnx_g, lnx_b,
                          q_attn_b, x_kv_b, x_proj_b, ln2_g, ln2_b, fc_b,
                          mlp_proj_b, scorer};
  unsigned short* sdst[14] = {c_ln1g, c_ln1b, c_catb, c_aprb, c_lnxg, c_lnxb,
                              c_qatb, c_xkvb, c_xprb, c_ln2g, c_ln2b, c_fcb,
                              c_mlpb, c_scor};
  int sn[14] = {1024,1024,3072,1024,1024,1024,1024,2048,1024,1024,1024,4096,1024,2048};
  for (int i=0;i<14;i++){ sc.src[i]=ssrc[i]; sc.dst[i]=sdst[i]; sc.n[i]=sn[i]; }
  k_prep_c<<<16384 + 14, 256, 0, stream>>>(enc, enc_c, hs, hidden, sc, flag);

  // --- self attention ---
  k_layernorm<<<S, 256, 0, stream>>>(hidden, c_ln1g, c_ln1b, xln);
  k_gemm64<<<dim3(3072/128, S/64), 256, 0, stream>>>(xln, wT_cattn, c_catb,
      qkv, nullptr, S, 3072, 1024, 4, flag, 2048, vt_self);
  k_flash3<0,0><<<dim3(32, NHEAD, 4), 256, 0, stream>>>(
      qkv, 3*H, qkv + 1024, 3*H, vt_self, nullptr, obuf, mlbuf, 80);
  k_comb<0><<<dim3(S/16, NHEAD), 256, 0, stream>>>(obuf, mlbuf, attnout, 80);
  k_gemm64s<<<dim3(1024/64, S/64, 1), 256, 0, stream>>>(attnout, wT_aproj, c_aprb,
      nullptr, hidden, nullptr, S, 1024, 1024, 1024, 2);

  // --- cross attention ---
  k_layernorm<<<S, 256, 0, stream>>>(hidden, c_lnxg, c_lnxb, xln);
  k_gemm64s<<<dim3(1024/64, S/64, 1), 256, 0, stream>>>(xln, wT_qattn, c_qatb,
      q2, nullptr, nullptr, S, 1024, 1024, 1024, 0);
  k_gemm64<<<dim3(2048/128, SEQE/64), 256, 0, stream>>>(enc_c, wT_xkv, c_xkvb,
      kvbuf, nullptr, SEQE, 2048, 1024, 4, flag, 1024, vt_cross);
  k_flash3<2,1><<<dim3(32, NHEAD, 4), 256, 0, stream>>>(
      q2, H, kvbuf, 2*H, vt_cross, c_scor, obuf, mlbuf, 83);
  k_comb<2><<<dim3(S/16, NHEAD), 256, 0, stream>>>(obuf, mlbuf, attnout, 83);
  k_gemm64s<<<dim3(1024/64, S/64, 1), 256, 0, stream>>>(attnout, wT_xproj, c_xprb,
      nullptr, hidden, nullptr, S, 1024, 1024, 1024, 2);

  // --- MLP ---
  k_layernorm<<<S, 256, 0, stream>>>(hidden, c_ln2g, c_ln2b, xln);
  k_gemm64<<<dim3(INNER/128, S/64), 256, 0, stream>>>(xln, wT_fc, c_fcb,
      fcbuf, nullptr, S, INNER, 1024, 1, flag, 0, nullptr);
  k_gemm64s<<<dim3(1024/64, S/64, 2), 256, 0, stream>>>(fcbuf, wT_mlp, c_mlpb,
      nullptr, nullptr, mlp_part, S, 1024, INNER, 2048, 5);
  k_finalize<<<(S*H)/256, 256, 0, stream>>>(mlp_part, mlp_part + (size_t)S*1024,
      hidden, out, flag);
}

// Round 11
// 450.193 us; speedup vs baseline: 1.3459x; 1.3459x over previous
//
#include <hip/hip_runtime.h>
#include <stdint.h>

#define H     1024
#define S     2048
#define SEQE  2048
#define NHEAD 16
#define HD    64
#define INNER 4096
#define EPSLN 1e-5f
#define LOG2E 1.44269504089f
#define SCALE2 (0.125f * LOG2E)

typedef __attribute__((ext_vector_type(8))) short short8;
typedef __attribute__((ext_vector_type(4))) float floatx4;

__device__ __forceinline__ float b2f(unsigned short u){
  union { unsigned int i; float f; } v; v.i = ((unsigned int)u) << 16; return v.f;
}
__device__ __forceinline__ unsigned short f2b(float f){
  union { float f; unsigned int i; } v; v.f = f;
  unsigned int x = v.i;
  unsigned int r = (x + 0x7FFFu + ((x >> 16) & 1u)) >> 16;
  return (unsigned short)r;
}
__device__ __forceinline__ float fexp2(float x){ return __builtin_amdgcn_exp2f(x); }
__device__ __forceinline__ float gelu_tanh(float x){
  float x3 = x*x*x;
  float t = tanhf(0.7978845608028654f*(x + 0.044715f*x3));
  return 0.5f*x*(1.0f+t);
}

// async global->LDS, 16B per lane; LDS dest = wave-uniform base + lane*16
__device__ __forceinline__ void gld16(const unsigned short* g, unsigned short* l){
  __builtin_amdgcn_global_load_lds(
      (const __attribute__((address_space(1))) unsigned int*)g,
      (__attribute__((address_space(3))) unsigned int*)l,
      16, 0, 0);
}

// ---------------- dtype sniff ----------------
__global__ __launch_bounds__(256) void k_sniff(
    const unsigned short* __restrict__ p, int* __restrict__ flag){
  __shared__ int any;
  if (threadIdx.x == 0) any = 0;
  __syncthreads();
  int bad = 0;
  for (int i = threadIdx.x; i < 8192; i += 256){
    float v = b2f(p[i]);
    if (!(fabsf(v) < 1e6f)) bad = 1;
  }
  if (bad) any = 1;
  __syncthreads();
  if (threadIdx.x == 0) flag[0] = any;
}

// ---------------- fused weight transposes ----------------
struct PrepT {
  const void* src[7];
  unsigned short* dst[7];
  int R[7], C[7];
  int pre[8];
};
__global__ __launch_bounds__(256) void k_prep_t(PrepT d, const int* __restrict__ flag){
  __shared__ unsigned short t[32][33];
  int b = blockIdx.x;
  int m = 0;
  while (b >= d.pre[m+1]) m++;
  int ti = b - d.pre[m];
  int R = d.R[m], C = d.C[m];
  int tx = threadIdx.x & 31, ty = threadIdx.x >> 5;
  int tilesx = C >> 5;
  int bc = (ti % tilesx) << 5, br = (ti / tilesx) << 5;
  const float* sf = (const float*)d.src[m];
  const unsigned short* sb = (const unsigned short*)d.src[m];
  unsigned short* dst = d.dst[m];
  int fl = flag[0];
  #pragma unroll
  for (int i = 0; i < 4; i++){
    size_t idx = (size_t)(br + ty + i*8) * C + bc + tx;
    t[ty + i*8][tx] = fl ? f2b(sf[idx]) : sb[idx];
  }
  __syncthreads();
  #pragma unroll
  for (int i = 0; i < 4; i++)
    dst[(size_t)(bc + ty + i*8) * R + br + tx] = t[tx][ty + i*8];
}

// ---------------- fused converts ----------------
struct SmallCvt {
  const void* src[16];
  unsigned short* dst[16];
  int n[16];
};
__global__ __launch_bounds__(256) void k_prep_c(
    const void* __restrict__ enc, unsigned short* __restrict__ enc_c,
    const void* __restrict__ hsv, float* __restrict__ hidden,
    SmallCvt sc, const int* __restrict__ flag){
  int b = blockIdx.x, tid = threadIdx.x;
  int fl = flag[0];
  if (b < 8192){
    int i = b*256 + tid;
    enc_c[i] = fl ? f2b(((const float*)enc)[i]) : ((const unsigned short*)enc)[i];
  } else if (b < 16384){
    int i = (b - 8192)*256 + tid;
    hidden[i] = fl ? ((const float*)hsv)[i] : b2f(((const unsigned short*)hsv)[i]);
  } else {
    int t = b - 16384;
    const float* sf = (const float*)sc.src[t];
    const unsigned short* sb = (const unsigned short*)sc.src[t];
    unsigned short* d = sc.dst[t];
    for (int i = tid; i < sc.n[t]; i += 256){
      float vv = fl ? sf[i] : b2f(sb[i]);
      if (t == 13) vv *= LOG2E;     // scorer pre-scaled to exp2 domain
      d[i] = f2b(vv);
    }
  }
}

// ---------------- LayerNorm ----------------
__global__ __launch_bounds__(256) void k_layernorm(
    const float* __restrict__ x,
    const unsigned short* __restrict__ g, const unsigned short* __restrict__ bb,
    unsigned short* __restrict__ y){
  __shared__ float scratch[4];
  int row = blockIdx.x, tid = threadIdx.x;
  float v[4];
  #pragma unroll
  for (int i=0;i<4;i++) v[i] = x[(size_t)row*H + tid + i*256];
  float s = v[0]+v[1]+v[2]+v[3];
  for (int o=32;o;o>>=1) s += __shfl_xor(s,o,64);
  int wid = tid>>6, lane = tid&63;
  if (lane==0) scratch[wid]=s;
  __syncthreads();
  float mu = (scratch[0]+scratch[1]+scratch[2]+scratch[3]) * (1.0f/H);
  __syncthreads();
  float q = 0.f;
  #pragma unroll
  for (int i=0;i<4;i++){ float d=v[i]-mu; q += d*d; }
  for (int o=32;o;o>>=1) q += __shfl_xor(q,o,64);
  if (lane==0) scratch[wid]=q;
  __syncthreads();
  float var = (scratch[0]+scratch[1]+scratch[2]+scratch[3]) * (1.0f/H);
  float rstd = rsqrtf(var + EPSLN);
  #pragma unroll
  for (int i=0;i<4;i++){
    int idx = tid + i*256;
    float o = (v[i]-mu)*rstd*b2f(g[idx]) + b2f(bb[idx]);
    y[(size_t)row*H + idx] = f2b(o);
  }
}

// ---------------- bf16 MFMA GEMM, 64x128 tile, BK=64, dbuf async staging ----------------
__global__ __launch_bounds__(256) void k_gemm64(
    const unsigned short* __restrict__ A, const unsigned short* __restrict__ BT,
    const unsigned short* __restrict__ bias,
    unsigned short* __restrict__ outb, float* __restrict__ resid,
    int M, int N, int K, int mode, const int* __restrict__ flag,
    int vcol0, unsigned short* __restrict__ vtout)
{
  __shared__ __align__(16) unsigned short As[2][64*64];
  __shared__ __align__(16) unsigned short Bs[2][128*64];
  int tid = threadIdx.x;
  int bm0 = blockIdx.y * 64, bn0 = blockIdx.x * 128;
  int wid = tid >> 6, lane = tid & 63;
  int wm = (wid & 1) * 32, wn = (wid >> 1) * 64;
  floatx4 acc[2][4] = {};

  const unsigned short* gp[6];
  int lofs[6];
  int aseg[6];
  int lrow = lane >> 3, lchunk = (lane & 7) ^ lrow;
  #pragma unroll
  for (int t = 0; t < 6; t++){
    int seg = wid * 6 + t;
    if (seg < 8){
      gp[t] = A + (size_t)(bm0 + seg*8 + lrow) * K + lchunk*8;
      lofs[t] = seg * 512;
      aseg[t] = 1;
    } else {
      int s = seg - 8;
      gp[t] = BT + (size_t)(bn0 + s*8 + lrow) * K + lchunk*8;
      lofs[t] = s * 512;
      aseg[t] = 0;
    }
  }

  #pragma unroll
  for (int t = 0; t < 6; t++)
    gld16(gp[t], (aseg[t] ? As[0] : Bs[0]) + lofs[t]);

  int mrow = lane & 15, quad = lane >> 4;
  int ib = 0;
  for (int kt = 0; kt < K; kt += 64, ib ^= 1){
    __syncthreads();
    if (kt + 64 < K){
      #pragma unroll
      for (int t = 0; t < 6; t++)
        gld16(gp[t] + kt + 64, (aseg[t] ? As[ib^1] : Bs[ib^1]) + lofs[t]);
    }
    const unsigned short* Ac = As[ib];
    const unsigned short* Bc = Bs[ib];
    #pragma unroll
    for (int k2 = 0; k2 < 2; k2++){
      short8 af[2], bf[4];
      #pragma unroll
      for (int i = 0; i < 2; i++){
        int r = wm + i*16 + mrow;
        int slot = (k2*4 + quad) ^ (r & 7);
        af[i] = *(const short8*)&Ac[r*64 + slot*8];
      }
      #pragma unroll
      for (int j = 0; j < 4; j++){
        int r = wn + j*16 + mrow;
        int slot = (k2*4 + quad) ^ (r & 7);
        bf[j] = *(const short8*)&Bc[r*64 + slot*8];
      }
      #pragma unroll
      for (int i = 0; i < 2; i++){
        #pragma unroll
        for (int j = 0; j < 4; j++){
          acc[i][j] = __builtin_amdgcn_mfma_f32_16x16x32_bf16(af[i], bf[j], acc[i][j], 0,0,0);
        }
      }
    }
  }

  int colb = mrow, rowb = quad * 4;
  #pragma unroll
  for (int i=0;i<2;i++){
    #pragma unroll
    for (int j=0;j<4;j++){
      int col = bn0 + wn + j*16 + colb;
      float bv = b2f(bias[col]);
      int row0 = bm0 + wm + i*16 + rowb;
      if (mode == 4 && col >= vcol0){
        ushort4 uv;
        uv.x = f2b(acc[i][j][0] + bv);
        uv.y = f2b(acc[i][j][1] + bv);
        uv.z = f2b(acc[i][j][2] + bv);
        uv.w = f2b(acc[i][j][3] + bv);
        *(ushort4*)(vtout + (size_t)(col - vcol0)*M + row0) = uv;
      } else {
        #pragma unroll
        for (int rr=0;rr<4;rr++){
          int row = row0 + rr;
          float v = acc[i][j][rr] + bv;
          size_t off = (size_t)row*N + col;
          if      (mode == 0 || mode == 4){ outb[off] = f2b(v); }
          else if (mode == 1){ outb[off] = f2b(gelu_tanh(v)); }
          else               { resid[off] += v; }     // mode 2 (single writer)
        }
      }
    }
  }
}

// ---------------- bf16 MFMA GEMM, 64x64 tile, non-split --------------------------------
// mode 0: out = bf16(v+bias)
// mode 2: resid[off] += v+bias (single writer)
// mode 3: out = (v+bias) + resid, stored per flag (fp32 or bf16)
__global__ __launch_bounds__(256) void k_gemm64s(
    const unsigned short* __restrict__ A, const unsigned short* __restrict__ BT,
    const unsigned short* __restrict__ bias,
    unsigned short* __restrict__ outb, float* __restrict__ resid,
    int M, int N, int K, int mode, const int* __restrict__ flag)
{
  __shared__ __align__(16) unsigned short As[2][64*64];
  __shared__ __align__(16) unsigned short Bs[2][64*64];
  int tid = threadIdx.x;
  int bm0 = blockIdx.y * 64, bn0 = blockIdx.x * 64;
  int wid = tid >> 6, lane = tid & 63;
  int wm = wid * 16;
  int fl = (mode == 3) ? flag[0] : 0;
  floatx4 acc[4] = {};

  const unsigned short* gp[4];
  int lofs[4];
  int aseg[4];
  int lrow = lane >> 3, lchunk = (lane & 7) ^ lrow;
  #pragma unroll
  for (int t = 0; t < 4; t++){
    int seg = wid * 4 + t;
    if (seg < 8){
      gp[t] = A + (size_t)(bm0 + seg*8 + lrow) * K + lchunk*8;
      lofs[t] = seg * 512;
      aseg[t] = 1;
    } else {
      int s = seg - 8;
      gp[t] = BT + (size_t)(bn0 + s*8 + lrow) * K + lchunk*8;
      lofs[t] = s * 512;
      aseg[t] = 0;
    }
  }

  #pragma unroll
  for (int t = 0; t < 4; t++)
    gld16(gp[t], (aseg[t] ? As[0] : Bs[0]) + lofs[t]);

  int mrow = lane & 15, quad = lane >> 4;
  int ib = 0;
  for (int kt = 0; kt < K; kt += 64, ib ^= 1){
    __syncthreads();
    if (kt + 64 < K){
      #pragma unroll
      for (int t = 0; t < 4; t++)
        gld16(gp[t] + kt + 64, (aseg[t] ? As[ib^1] : Bs[ib^1]) + lofs[t]);
    }
    const unsigned short* Ac = As[ib];
    const unsigned short* Bc = Bs[ib];
    #pragma unroll
    for (int k2 = 0; k2 < 2; k2++){
      short8 af, bf[4];
      {
        int r = wm + mrow;
        int slot = (k2*4 + quad) ^ (r & 7);
        af = *(const short8*)&Ac[r*64 + slot*8];
      }
      #pragma unroll
      for (int j = 0; j < 4; j++){
        int r = j*16 + mrow;
        int slot = (k2*4 + quad) ^ (r & 7);
        bf[j] = *(const short8*)&Bc[r*64 + slot*8];
      }
      #pragma unroll
      for (int j = 0; j < 4; j++)
        acc[j] = __builtin_amdgcn_mfma_f32_16x16x32_bf16(af, bf[j], acc[j], 0,0,0);
    }
  }

  int colb = mrow, rowb = quad * 4;
  #pragma unroll
  for (int j=0;j<4;j++){
    int col = bn0 + j*16 + colb;
    float bv = b2f(bias[col]);
    int row0 = bm0 + wm + rowb;
    #pragma unroll
    for (int rr=0;rr<4;rr++){
      int row = row0 + rr;
      float v = acc[j][rr] + bv;
      size_t off = (size_t)row*N + col;
      if      (mode == 0){ outb[off] = f2b(v); }
      else if (mode == 2){ resid[off] += v; }
      else {
        float o = v + resid[off];
        if (fl) ((float*)outb)[off] = o;
        else    outb[off] = f2b(o);
      }
    }
  }
}

// ---------------- split-K flash attention (K dbuf, V single-buf, 2-barrier) ----------
template<int CA, int SCOR>
__global__ __launch_bounds__(256) void k_flash2(
    const unsigned short* __restrict__ qb, int qstride,
    const unsigned short* __restrict__ kb, int kstride,
    const unsigned short* __restrict__ vt,
    const unsigned short* __restrict__ scorer,
    unsigned short* __restrict__ obuf, float* __restrict__ mlbuf, int TOTS)
{
  int t = blockIdx.x, h = blockIdx.y, sp = blockIdx.z;
  int klmax0 = 64*t + 64 + CA; if (klmax0 > S) klmax0 = S;
  int nch = (klmax0 + 63) >> 6;
  int nsp = (nch + 7) >> 3;
  if (sp >= nsp) return;
  int base = 0;
  for (int i = 0; i < t; i++){
    int km = 64*i + 64 + CA; if (km > S) km = S;
    base += (((km + 63) >> 6) + 7) >> 3;
  }
  int pidx = h*TOTS + base + sp;
  int c0 = sp*8, c1 = c0 + 8; if (c1 > nch) c1 = nch;

  __shared__ __align__(16) unsigned short Ks[2][64*64];   // 16 KB (dbuf)
  __shared__ __align__(16) unsigned short VTs[64*64];     //  8 KB (single)
  __shared__ __align__(16) unsigned short Ps[4][16*72];   // 9.2 KB
  __shared__ float scs[2][64];
  int tid = threadIdx.x;
  int q0 = t*64;
  int w = tid >> 6, lane = tid & 63;
  int cn = lane & 15, quad = lane >> 4, kq = quad * 8;
  unsigned short* Pw = Ps[w];
  int srow0 = w*16;
  int lr = lane >> 3;
  int lc = ((lane & 7) ^ lr) * 8;
  const unsigned short* kg0 = kb + (size_t)(srow0 + lr) * kstride + h*HD + lc;
  const unsigned short* kg1 = kb + (size_t)(srow0 + 8 + lr) * kstride + h*HD + lc;
  const unsigned short* vg0 = vt + (size_t)(h*HD + srow0 + lr) * S + lc;
  const unsigned short* vg1 = vt + (size_t)(h*HD + srow0 + 8 + lr) * S + lc;

  const unsigned short* qrow = qb + (size_t)(q0 + w*16 + cn) * qstride + h*HD;
  short8 qf0 = *(const short8*)(qrow + kq);
  short8 qf1 = *(const short8*)(qrow + kq + 32);
  floatx4 oacc[4] = {};
  float l_lane[4] = {0,0,0,0};
  float m_w = -1.0e38f;
  int qmr = q0 + w*16 + quad*4;

  // prologue: K and scorer for chunk c0 into buffer 0
  {
    int kc = c0 * 64;
    gld16(kg0 + (size_t)kc * kstride, Ks[0] + srow0*64);
    gld16(kg1 + (size_t)kc * kstride, Ks[0] + (srow0 + 8)*64);
    if (SCOR && tid < 64) scs[0][tid] = b2f(scorer[kc + tid]);
  }

  int ib = 0;
  for (int ci = c0; ci < c1; ci++, ib ^= 1){
    int kc = ci * 64;
    __syncthreads();                 // barrier1: prev chunk fully done; K_ci drained
    // stage V_ci (single buffer — safe after barrier1), K/scorer for ci+1
    gld16(vg0 + kc, VTs + srow0*64);
    gld16(vg1 + kc, VTs + (srow0 + 8)*64);
    if (ci + 1 < c1){
      int kn2 = (ci + 1) * 64;
      gld16(kg0 + (size_t)kn2 * kstride, Ks[ib^1] + srow0*64);
      gld16(kg1 + (size_t)kn2 * kstride, Ks[ib^1] + (srow0 + 8)*64);
      if (SCOR && tid < 64) scs[ib^1][tid] = b2f(scorer[kn2 + tid]);
    }
    const unsigned short* Kc = Ks[ib];
    const float* scc = scs[ib];

    floatx4 sv[4] = {};
    #pragma unroll
    for (int t4=0;t4<4;t4++){
      int rr = t4*16 + cn;
      int s0 = ((quad    ) ^ (rr & 7)) * 8;
      int s1 = ((quad + 4) ^ (rr & 7)) * 8;
      short8 b0 = *(const short8*)&Kc[rr*64 + s0];
      short8 b1 = *(const short8*)&Kc[rr*64 + s1];
      sv[t4] = __builtin_amdgcn_mfma_f32_16x16x32_bf16(qf0, b0, sv[t4], 0,0,0);
      sv[t4] = __builtin_amdgcn_mfma_f32_16x16x32_bf16(qf1, b1, sv[t4], 0,0,0);
    }

    float vals[16];
    float lmax = -1.0e38f;
    if (kc + 63 > q0 + w*16 + CA){          // wave-uniform: diagonal (masked) chunk
      #pragma unroll
      for (int t4=0;t4<4;t4++){
        #pragma unroll
        for (int r=0;r<4;r++){
          float s = sv[t4][r] * SCALE2;
          if (SCOR) s += scc[t4*16 + cn];
          int kn = kc + t4*16 + cn;
          s = (kn <= qmr + r + CA) ? s : -1.0e38f;
          vals[t4*4+r] = s;
          lmax = fmaxf(lmax, s);
        }
      }
    } else {
      #pragma unroll
      for (int t4=0;t4<4;t4++){
        #pragma unroll
        for (int r=0;r<4;r++){
          float s = sv[t4][r] * SCALE2;
          if (SCOR) s += scc[t4*16 + cn];
          vals[t4*4+r] = s;
          lmax = fmaxf(lmax, s);
        }
      }
    }
    lmax = fmaxf(lmax, __shfl_xor(lmax,1,64));
    lmax = fmaxf(lmax, __shfl_xor(lmax,2,64));
    lmax = fmaxf(lmax, __shfl_xor(lmax,4,64));
    lmax = fmaxf(lmax, __shfl_xor(lmax,8,64));
    // branchless rescale
    float mnew = fmaxf(m_w, lmax);
    float al = fexp2(m_w - mnew);
    m_w = mnew;
    #pragma unroll
    for (int r=0;r<4;r++) l_lane[r] *= al;
    #pragma unroll
    for (int t2=0;t2<4;t2++){
      #pragma unroll
      for (int r=0;r<4;r++) oacc[t2][r] *= al;
    }
    #pragma unroll
    for (int t4=0;t4<4;t4++){
      #pragma unroll
      for (int r=0;r<4;r++){
        float e = fexp2(vals[t4*4+r] - m_w);
        l_lane[r] += e;
        Pw[(quad*4+r)*72 + t4*16 + cn] = f2b(e);
      }
    }
    __syncthreads();                 // barrier2: V_ci visible to all waves
    short8 pf0 = *(const short8*)&Pw[cn*72 + kq];
    short8 pf1 = *(const short8*)&Pw[cn*72 + kq + 32];
    #pragma unroll
    for (int t2=0;t2<4;t2++){
      int rr = t2*16 + cn;
      int s0 = ((quad    ) ^ (rr & 7)) * 8;
      int s1 = ((quad + 4) ^ (rr & 7)) * 8;
      short8 v0 = *(const short8*)&VTs[rr*64 + s0];
      short8 v1 = *(const short8*)&VTs[rr*64 + s1];
      oacc[t2] = __builtin_amdgcn_mfma_f32_16x16x32_bf16(pf0, v0, oacc[t2], 0,0,0);
      oacc[t2] = __builtin_amdgcn_mfma_f32_16x16x32_bf16(pf1, v1, oacc[t2], 0,0,0);
    }
  }

  float lrow[4];
  #pragma unroll
  for (int r=0;r<4;r++){
    float l = l_lane[r];
    l += __shfl_xor(l,1,64); l += __shfl_xor(l,2,64);
    l += __shfl_xor(l,4,64); l += __shfl_xor(l,8,64);
    lrow[r] = l;
  }
  size_t ob = (size_t)pidx*4096 + (size_t)(w*16 + quad*4)*64;
  #pragma unroll
  for (int t2=0;t2<4;t2++){
    #pragma unroll
    for (int r=0;r<4;r++)
      obuf[ob + r*64 + t2*16 + cn] = f2b(oacc[t2][r]);
  }
  if (cn == 0){
    #pragma unroll
    for (int r=0;r<4;r++){
      int row64 = w*16 + quad*4 + r;
      mlbuf[((size_t)pidx*64 + row64)*2]   = m_w;
      mlbuf[((size_t)pidx*64 + row64)*2+1] = lrow[r];
    }
  }
}

// ---------------- split-K combine ----------------
template<int CA>
__global__ __launch_bounds__(256) void k_comb(
    const unsigned short* __restrict__ obuf, const float* __restrict__ mlbuf,
    unsigned short* __restrict__ out, int TOTS)
{
  int h = blockIdx.y;
  int row = blockIdx.x*16 + (threadIdx.x >> 4);
  int d0 = (threadIdx.x & 15) * 4;
  int t = row >> 6;
  int klmax0 = 64*t + 64 + CA; if (klmax0 > S) klmax0 = S;
  int nch = (klmax0 + 63) >> 6;
  int nsp = (nch + 7) >> 3;
  int base = 0;
  for (int i = 0; i < t; i++){
    int km = 64*i + 64 + CA; if (km > S) km = S;
    base += (((km + 63) >> 6) + 7) >> 3;
  }
  int row64 = row & 63;
  float mp[4], lp[4];
  float M = -1.0e38f;
  for (int p = 0; p < nsp; p++){
    int pi = h*TOTS + base + p;
    mp[p] = mlbuf[((size_t)pi*64 + row64)*2];
    lp[p] = mlbuf[((size_t)pi*64 + row64)*2+1];
    M = fmaxf(M, mp[p]);
  }
  float L = 0.f;
  float o0=0.f,o1=0.f,o2=0.f,o3=0.f;
  for (int p = 0; p < nsp; p++){
    int pi = h*TOTS + base + p;
    float wgt = fexp2(mp[p] - M);
    L += lp[p]*wgt;
    const unsigned short* op = obuf + (size_t)pi*4096 + row64*64 + d0;
    o0 += b2f(op[0])*wgt; o1 += b2f(op[1])*wgt;
    o2 += b2f(op[2])*wgt; o3 += b2f(op[3])*wgt;
  }
  float inv = 1.0f / L;
  size_t oo = (size_t)row*H + h*HD + d0;
  out[oo]   = f2b(o0*inv); out[oo+1] = f2b(o1*inv);
  out[oo+2] = f2b(o2*inv); out[oo+3] = f2b(o3*inv);
}

extern "C" void kernel_launch(void* const* d_in, const int* in_sizes, int n_in,
                              void* d_out, int out_size, void* d_ws, size_t ws_size,
                              hipStream_t stream)
{
  const void* hs          = d_in[0];
  const void* enc         = d_in[1];
  const void* scorer      = d_in[2];
  const void* ln1_g       = d_in[3];
  const void* ln1_b       = d_in[4];
  const void* c_attn_w    = d_in[5];
  const void* c_attn_b    = d_in[6];
  const void* attn_proj_w = d_in[7];
  const void* attn_proj_b = d_in[8];
  const void* lnx_g       = d_in[9];
  const void* lnx_b       = d_in[10];
  const void* q_attn_w    = d_in[11];
  const void* q_attn_b    = d_in[12];
  const void* x_kv_w      = d_in[13];
  const void* x_kv_b      = d_in[14];
  const void* x_proj_w    = d_in[15];
  const void* x_proj_b    = d_in[16];
  const void* ln2_g       = d_in[17];
  const void* ln2_b       = d_in[18];
  const void* fc_w        = d_in[19];
  const void* fc_b        = d_in[20];
  const void* mlp_proj_w  = d_in[21];
  const void* mlp_proj_b  = d_in[22];
  unsigned short* out = (unsigned short*)d_out;

  char* ws = (char*)d_ws; size_t off = 0;
  auto alloc = [&](size_t bytes)->void*{
    void* p = ws + off; off += (bytes + 255) & ~(size_t)255; return p;
  };
  unsigned short* wT_cattn = (unsigned short*)alloc((size_t)3072*1024*2);
  unsigned short* wT_aproj = (unsigned short*)alloc((size_t)1024*1024*2);
  unsigned short* wT_qattn = (unsigned short*)alloc((size_t)1024*1024*2);
  unsigned short* wT_xkv   = (unsigned short*)alloc((size_t)2048*1024*2);
  unsigned short* wT_xproj = (unsigned short*)alloc((size_t)1024*1024*2);
  unsigned short* wT_fc    = (unsigned short*)alloc((size_t)4096*1024*2);
  unsigned short* wT_mlp   = (unsigned short*)alloc((size_t)1024*4096*2);
  unsigned short* enc_c    = (unsigned short*)alloc((size_t)SEQE*H*2);
  unsigned short* canon    = (unsigned short*)alloc((size_t)32768*2);
  unsigned short* xln      = (unsigned short*)alloc((size_t)S*H*2);
  unsigned short* qkv      = (unsigned short*)alloc((size_t)S*3*H*2);
  unsigned short* attnout  = (unsigned short*)alloc((size_t)S*H*2);
  unsigned short* q2       = (unsigned short*)alloc((size_t)S*H*2);
  unsigned short* kvbuf    = (unsigned short*)alloc((size_t)SEQE*2*H*2);
  unsigned short* vt_self  = (unsigned short*)alloc((size_t)H*S*2);
  unsigned short* vt_cross = (unsigned short*)alloc((size_t)H*SEQE*2);
  unsigned short* fcbuf    = (unsigned short*)alloc((size_t)S*INNER*2);
  float*          hidden   = (float*)alloc((size_t)S*H*4);
  int*            flag     = (int*)alloc(256);

  unsigned short* obuf  = fcbuf;
  float*          mlbuf = (float*)(fcbuf + (size_t)16*83*4096);

  unsigned short* p = canon;
  auto carve = [&](int n)->unsigned short*{ unsigned short* q = p; p += n; return q; };
  unsigned short* c_ln1g = carve(1024); unsigned short* c_ln1b = carve(1024);
  unsigned short* c_catb = carve(3072); unsigned short* c_aprb = carve(1024);
  unsigned short* c_lnxg = carve(1024); unsigned short* c_lnxb = carve(1024);
  unsigned short* c_qatb = carve(1024); unsigned short* c_xkvb = carve(2048);
  unsigned short* c_xprb = carve(1024); unsigned short* c_ln2g = carve(1024);
  unsigned short* c_ln2b = carve(1024); unsigned short* c_fcb  = carve(4096);
  unsigned short* c_mlpb = carve(1024); unsigned short* c_scor = carve(2048);

  k_sniff<<<1, 256, 0, stream>>>((const unsigned short*)hs, flag);

  PrepT pt{};
  const void* tsrc[7] = {c_attn_w, attn_proj_w, q_attn_w, x_kv_w, x_proj_w, fc_w, mlp_proj_w};
  unsigned short* tdst[7] = {wT_cattn, wT_aproj, wT_qattn, wT_xkv, wT_xproj, wT_fc, wT_mlp};
  int tR[7] = {1024,1024,1024,1024,1024,1024,4096};
  int tC[7] = {3072,1024,1024,2048,1024,4096,1024};
  int acc_t = 0;
  for (int i=0;i<7;i++){
    pt.src[i]=tsrc[i]; pt.dst[i]=tdst[i]; pt.R[i]=tR[i]; pt.C[i]=tC[i];
    pt.pre[i]=acc_t; acc_t += (tC[i]>>5)*(tR[i]>>5);
  }
  pt.pre[7]=acc_t;
  k_prep_t<<<acc_t, 256, 0, stream>>>(pt, flag);

  SmallCvt sc{};
  const void* ssrc[14] = {ln1_g, ln1_b, c_attn_b, attn_proj_b, lnx_g, lnx_b,
                          q_attn_b, x_kv_b, x_proj_b, ln2_g, ln2_b, fc_b,
                          mlp_proj_b, scorer};
  unsigned short* sdst[14] = {c_ln1g, c_ln1b, c_catb, c_aprb, c_lnxg, c_lnxb,
                              c_qatb, c_xkvb, c_xprb, c_ln2g, c_ln2b, c_fcb,
                              c_mlpb, c_scor};
  int sn[14] = {1024,1024,3072,1024,1024,1024,1024,2048,1024,1024,1024,4096,1024,2048};
  for (int i=0;i<14;i++){ sc.src[i]=ssrc[i]; sc.dst[i]=sdst[i]; sc.n[i]=sn[i]; }
  k_prep_c<<<16384 + 14, 256, 0, stream>>>(enc, enc_c, hs, hidden, sc, flag);

  // --- self attention ---
  k_layernorm<<<S, 256, 0, stream>>>(hidden, c_ln1g, c_ln1b, xln);
  k_gemm64<<<dim3(3072/128, S/64), 256, 0, stream>>>(xln, wT_cattn, c_catb,
      qkv, nullptr, S, 3072, 1024, 4, flag, 2048, vt_self);
  k_flash2<0,0><<<dim3(32, NHEAD, 4), 256, 0, stream>>>(
      qkv, 3*H, qkv + 1024, 3*H, vt_self, nullptr, obuf, mlbuf, 80);
  k_comb<0><<<dim3(S/16, NHEAD), 256, 0, stream>>>(obuf, mlbuf, attnout, 80);
  k_gemm64s<<<dim3(1024/64, S/64), 256, 0, stream>>>(attnout, wT_aproj, c_aprb,
      nullptr, hidden, S, 1024, 1024, 2, flag);

  // --- cross attention ---
  k_layernorm<<<S, 256, 0, stream>>>(hidden, c_lnxg, c_lnxb, xln);
  k_gemm64s<<<dim3(1024/64, S/64), 256, 0, stream>>>(xln, wT_qattn, c_qatb,
      q2, nullptr, S, 1024, 1024, 0, flag);
  k_gemm64<<<dim3(2048/128, SEQE/64), 256, 0, stream>>>(enc_c, wT_xkv, c_xkvb,
      kvbuf, nullptr, SEQE, 2048, 1024, 4, flag, 1024, vt_cross);
  k_flash2<2,1><<<dim3(32, NHEAD, 4), 256, 0, stream>>>(
      q2, H, kvbuf, 2*H, vt_cross, c_scor, obuf, mlbuf, 83);
  k_comb<2><<<dim3(S/16, NHEAD), 256, 0, stream>>>(obuf, mlbuf, attnout, 83);
  k_gemm64s<<<dim3(1024/64, S/64), 256, 0, stream>>>(attnout, wT_xproj, c_xprb,
      nullptr, hidden, S, 1024, 1024, 2, flag);

  // --- MLP ---
  k_layernorm<<<S, 256, 0, stream>>>(hidden, c_ln2g, c_ln2b, xln);
  k_gemm64<<<dim3(INNER/128, S/64), 256, 0, stream>>>(xln, wT_fc, c_fcb,
      fcbuf, nullptr, S, INNER, 1024, 1, flag, 0, nullptr);
  k_gemm64s<<<dim3(1024/64, S/64), 256, 0, stream>>>(fcbuf, wT_mlp, c_mlpb,
      out, hidden, S, 1024, INNER, 3, flag);
}

// Round 12
// 437.985 us; speedup vs baseline: 1.3835x; 1.0279x over previous
//
#include <hip/hip_runtime.h>
#include <stdint.h>

#define H     1024
#define S     2048
#define SEQE  2048
#define NHEAD 16
#define HD    64
#define INNER 4096
#define EPSLN 1e-5f
#define LOG2E 1.44269504089f
#define SCALE2 (0.125f * LOG2E)

typedef __attribute__((ext_vector_type(8))) short short8;
typedef __attribute__((ext_vector_type(4))) float floatx4;

__device__ __forceinline__ float b2f(unsigned short u){
  union { unsigned int i; float f; } v; v.i = ((unsigned int)u) << 16; return v.f;
}
__device__ __forceinline__ unsigned short f2b(float f){
  union { float f; unsigned int i; } v; v.f = f;
  unsigned int x = v.i;
  unsigned int r = (x + 0x7FFFu + ((x >> 16) & 1u)) >> 16;
  return (unsigned short)r;
}
__device__ __forceinline__ float fexp2(float x){ return __builtin_amdgcn_exp2f(x); }
__device__ __forceinline__ float gelu_tanh(float x){
  float x3 = x*x*x;
  float t = tanhf(0.7978845608028654f*(x + 0.044715f*x3));
  return 0.5f*x*(1.0f+t);
}

// async global->LDS, 16B per lane; LDS dest = wave-uniform base + lane*16
__device__ __forceinline__ void gld16(const unsigned short* g, unsigned short* l){
  __builtin_amdgcn_global_load_lds(
      (const __attribute__((address_space(1))) unsigned int*)g,
      (__attribute__((address_space(3))) unsigned int*)l,
      16, 0, 0);
}

// ---------------- dtype sniff ----------------
__global__ __launch_bounds__(256) void k_sniff(
    const unsigned short* __restrict__ p, int* __restrict__ flag){
  __shared__ int any;
  if (threadIdx.x == 0) any = 0;
  __syncthreads();
  int bad = 0;
  for (int i = threadIdx.x; i < 8192; i += 256){
    float v = b2f(p[i]);
    if (!(fabsf(v) < 1e6f)) bad = 1;
  }
  if (bad) any = 1;
  __syncthreads();
  if (threadIdx.x == 0) flag[0] = any;
}

// ---------------- fused weight transposes ----------------
struct PrepT {
  const void* src[7];
  unsigned short* dst[7];
  int R[7], C[7];
  int pre[8];
};
__global__ __launch_bounds__(256) void k_prep_t(PrepT d, const int* __restrict__ flag){
  __shared__ unsigned short t[32][33];
  int b = blockIdx.x;
  int m = 0;
  while (b >= d.pre[m+1]) m++;
  int ti = b - d.pre[m];
  int R = d.R[m], C = d.C[m];
  int tx = threadIdx.x & 31, ty = threadIdx.x >> 5;
  int tilesx = C >> 5;
  int bc = (ti % tilesx) << 5, br = (ti / tilesx) << 5;
  const float* sf = (const float*)d.src[m];
  const unsigned short* sb = (const unsigned short*)d.src[m];
  unsigned short* dst = d.dst[m];
  int fl = flag[0];
  #pragma unroll
  for (int i = 0; i < 4; i++){
    size_t idx = (size_t)(br + ty + i*8) * C + bc + tx;
    t[ty + i*8][tx] = fl ? f2b(sf[idx]) : sb[idx];
  }
  __syncthreads();
  #pragma unroll
  for (int i = 0; i < 4; i++)
    dst[(size_t)(bc + ty + i*8) * R + br + tx] = t[tx][ty + i*8];
}

// ---------------- fused converts ----------------
struct SmallCvt {
  const void* src[16];
  unsigned short* dst[16];
  int n[16];
};
__global__ __launch_bounds__(256) void k_prep_c(
    const void* __restrict__ enc, unsigned short* __restrict__ enc_c,
    const void* __restrict__ hsv, float* __restrict__ hidden,
    SmallCvt sc, const int* __restrict__ flag){
  int b = blockIdx.x, tid = threadIdx.x;
  int fl = flag[0];
  if (b < 8192){
    int i = b*256 + tid;
    enc_c[i] = fl ? f2b(((const float*)enc)[i]) : ((const unsigned short*)enc)[i];
  } else if (b < 16384){
    int i = (b - 8192)*256 + tid;
    hidden[i] = fl ? ((const float*)hsv)[i] : b2f(((const unsigned short*)hsv)[i]);
  } else {
    int t = b - 16384;
    const float* sf = (const float*)sc.src[t];
    const unsigned short* sb = (const unsigned short*)sc.src[t];
    unsigned short* d = sc.dst[t];
    for (int i = tid; i < sc.n[t]; i += 256){
      float vv = fl ? sf[i] : b2f(sb[i]);
      if (t == 13) vv *= LOG2E;     // scorer pre-scaled to exp2 domain
      d[i] = f2b(vv);
    }
  }
}

// ---------------- LayerNorm ----------------
__global__ __launch_bounds__(256) void k_layernorm(
    const float* __restrict__ x,
    const unsigned short* __restrict__ g, const unsigned short* __restrict__ bb,
    unsigned short* __restrict__ y){
  __shared__ float scratch[4];
  int row = blockIdx.x, tid = threadIdx.x;
  float v[4];
  #pragma unroll
  for (int i=0;i<4;i++) v[i] = x[(size_t)row*H + tid + i*256];
  float s = v[0]+v[1]+v[2]+v[3];
  for (int o=32;o;o>>=1) s += __shfl_xor(s,o,64);
  int wid = tid>>6, lane = tid&63;
  if (lane==0) scratch[wid]=s;
  __syncthreads();
  float mu = (scratch[0]+scratch[1]+scratch[2]+scratch[3]) * (1.0f/H);
  __syncthreads();
  float q = 0.f;
  #pragma unroll
  for (int i=0;i<4;i++){ float d=v[i]-mu; q += d*d; }
  for (int o=32;o;o>>=1) q += __shfl_xor(q,o,64);
  if (lane==0) scratch[wid]=q;
  __syncthreads();
  float var = (scratch[0]+scratch[1]+scratch[2]+scratch[3]) * (1.0f/H);
  float rstd = rsqrtf(var + EPSLN);
  #pragma unroll
  for (int i=0;i<4;i++){
    int idx = tid + i*256;
    float o = (v[i]-mu)*rstd*b2f(g[idx]) + b2f(bb[idx]);
    y[(size_t)row*H + idx] = f2b(o);
  }
}

// ---------------- bf16 MFMA GEMM, 64x128 tile, BK=64, dbuf async staging ----------------
__global__ __launch_bounds__(256) void k_gemm64(
    const unsigned short* __restrict__ A, const unsigned short* __restrict__ BT,
    const unsigned short* __restrict__ bias,
    unsigned short* __restrict__ outb, float* __restrict__ resid,
    int M, int N, int K, int mode, const int* __restrict__ flag,
    int vcol0, unsigned short* __restrict__ vtout)
{
  __shared__ __align__(16) unsigned short As[2][64*64];
  __shared__ __align__(16) unsigned short Bs[2][128*64];
  int tid = threadIdx.x;
  int bm0 = blockIdx.y * 64, bn0 = blockIdx.x * 128;
  int wid = tid >> 6, lane = tid & 63;
  int wm = (wid & 1) * 32, wn = (wid >> 1) * 64;
  floatx4 acc[2][4] = {};

  const unsigned short* gp[6];
  int lofs[6];
  int aseg[6];
  int lrow = lane >> 3, lchunk = (lane & 7) ^ lrow;
  #pragma unroll
  for (int t = 0; t < 6; t++){
    int seg = wid * 6 + t;
    if (seg < 8){
      gp[t] = A + (size_t)(bm0 + seg*8 + lrow) * K + lchunk*8;
      lofs[t] = seg * 512;
      aseg[t] = 1;
    } else {
      int s = seg - 8;
      gp[t] = BT + (size_t)(bn0 + s*8 + lrow) * K + lchunk*8;
      lofs[t] = s * 512;
      aseg[t] = 0;
    }
  }

  #pragma unroll
  for (int t = 0; t < 6; t++)
    gld16(gp[t], (aseg[t] ? As[0] : Bs[0]) + lofs[t]);

  int mrow = lane & 15, quad = lane >> 4;
  int ib = 0;
  for (int kt = 0; kt < K; kt += 64, ib ^= 1){
    __syncthreads();
    if (kt + 64 < K){
      #pragma unroll
      for (int t = 0; t < 6; t++)
        gld16(gp[t] + kt + 64, (aseg[t] ? As[ib^1] : Bs[ib^1]) + lofs[t]);
    }
    const unsigned short* Ac = As[ib];
    const unsigned short* Bc = Bs[ib];
    #pragma unroll
    for (int k2 = 0; k2 < 2; k2++){
      short8 af[2], bf[4];
      #pragma unroll
      for (int i = 0; i < 2; i++){
        int r = wm + i*16 + mrow;
        int slot = (k2*4 + quad) ^ (r & 7);
        af[i] = *(const short8*)&Ac[r*64 + slot*8];
      }
      #pragma unroll
      for (int j = 0; j < 4; j++){
        int r = wn + j*16 + mrow;
        int slot = (k2*4 + quad) ^ (r & 7);
        bf[j] = *(const short8*)&Bc[r*64 + slot*8];
      }
      #pragma unroll
      for (int i = 0; i < 2; i++){
        #pragma unroll
        for (int j = 0; j < 4; j++){
          acc[i][j] = __builtin_amdgcn_mfma_f32_16x16x32_bf16(af[i], bf[j], acc[i][j], 0,0,0);
        }
      }
    }
  }

  int colb = mrow, rowb = quad * 4;
  #pragma unroll
  for (int i=0;i<2;i++){
    #pragma unroll
    for (int j=0;j<4;j++){
      int col = bn0 + wn + j*16 + colb;
      float bv = b2f(bias[col]);
      int row0 = bm0 + wm + i*16 + rowb;
      if (mode == 4 && col >= vcol0){
        ushort4 uv;
        uv.x = f2b(acc[i][j][0] + bv);
        uv.y = f2b(acc[i][j][1] + bv);
        uv.z = f2b(acc[i][j][2] + bv);
        uv.w = f2b(acc[i][j][3] + bv);
        *(ushort4*)(vtout + (size_t)(col - vcol0)*M + row0) = uv;
      } else {
        #pragma unroll
        for (int rr=0;rr<4;rr++){
          int row = row0 + rr;
          float v = acc[i][j][rr] + bv;
          size_t off = (size_t)row*N + col;
          if      (mode == 0 || mode == 4){ outb[off] = f2b(v); }
          else if (mode == 1){ outb[off] = f2b(gelu_tanh(v)); }
          else               { resid[off] += v; }     // mode 2 (single writer)
        }
      }
    }
  }
}

// ---------------- bf16 MFMA GEMM, 64x64 tile, non-split --------------------------------
__global__ __launch_bounds__(256) void k_gemm64s(
    const unsigned short* __restrict__ A, const unsigned short* __restrict__ BT,
    const unsigned short* __restrict__ bias,
    unsigned short* __restrict__ outb, float* __restrict__ resid,
    int M, int N, int K, int mode, const int* __restrict__ flag)
{
  __shared__ __align__(16) unsigned short As[2][64*64];
  __shared__ __align__(16) unsigned short Bs[2][64*64];
  int tid = threadIdx.x;
  int bm0 = blockIdx.y * 64, bn0 = blockIdx.x * 64;
  int wid = tid >> 6, lane = tid & 63;
  int wm = wid * 16;
  int fl = (mode == 3) ? flag[0] : 0;
  floatx4 acc[4] = {};

  const unsigned short* gp[4];
  int lofs[4];
  int aseg[4];
  int lrow = lane >> 3, lchunk = (lane & 7) ^ lrow;
  #pragma unroll
  for (int t = 0; t < 4; t++){
    int seg = wid * 4 + t;
    if (seg < 8){
      gp[t] = A + (size_t)(bm0 + seg*8 + lrow) * K + lchunk*8;
      lofs[t] = seg * 512;
      aseg[t] = 1;
    } else {
      int s = seg - 8;
      gp[t] = BT + (size_t)(bn0 + s*8 + lrow) * K + lchunk*8;
      lofs[t] = s * 512;
      aseg[t] = 0;
    }
  }

  #pragma unroll
  for (int t = 0; t < 4; t++)
    gld16(gp[t], (aseg[t] ? As[0] : Bs[0]) + lofs[t]);

  int mrow = lane & 15, quad = lane >> 4;
  int ib = 0;
  for (int kt = 0; kt < K; kt += 64, ib ^= 1){
    __syncthreads();
    if (kt + 64 < K){
      #pragma unroll
      for (int t = 0; t < 4; t++)
        gld16(gp[t] + kt + 64, (aseg[t] ? As[ib^1] : Bs[ib^1]) + lofs[t]);
    }
    const unsigned short* Ac = As[ib];
    const unsigned short* Bc = Bs[ib];
    #pragma unroll
    for (int k2 = 0; k2 < 2; k2++){
      short8 af, bf[4];
      {
        int r = wm + mrow;
        int slot = (k2*4 + quad) ^ (r & 7);
        af = *(const short8*)&Ac[r*64 + slot*8];
      }
      #pragma unroll
      for (int j = 0; j < 4; j++){
        int r = j*16 + mrow;
        int slot = (k2*4 + quad) ^ (r & 7);
        bf[j] = *(const short8*)&Bc[r*64 + slot*8];
      }
      #pragma unroll
      for (int j = 0; j < 4; j++)
        acc[j] = __builtin_amdgcn_mfma_f32_16x16x32_bf16(af, bf[j], acc[j], 0,0,0);
    }
  }

  int colb = mrow, rowb = quad * 4;
  #pragma unroll
  for (int j=0;j<4;j++){
    int col = bn0 + j*16 + colb;
    float bv = b2f(bias[col]);
    int row0 = bm0 + wm + rowb;
    #pragma unroll
    for (int rr=0;rr<4;rr++){
      int row = row0 + rr;
      float v = acc[j][rr] + bv;
      size_t off = (size_t)row*N + col;
      if      (mode == 0){ outb[off] = f2b(v); }
      else if (mode == 2){ resid[off] += v; }
      else {
        float o = v + resid[off];
        if (fl) ((float*)outb)[off] = o;
        else    outb[off] = f2b(o);
      }
    }
  }
}

// ---------------- split-K flash attention (no online max: scores bounded) -------------
// m == 0 always: exp2 of raw (scaled) scores; normalization at combine makes it exact.
// Removes the 4-shfl serial max reduce + rescale chain per chunk.
template<int CA, int SCOR>
__global__ __launch_bounds__(256) void k_flash2(
    const unsigned short* __restrict__ qb, int qstride,
    const unsigned short* __restrict__ kb, int kstride,
    const unsigned short* __restrict__ vt,
    const unsigned short* __restrict__ scorer,
    unsigned short* __restrict__ obuf, float* __restrict__ lbuf, int TOTS)
{
  int t = blockIdx.x, h = blockIdx.y, sp = blockIdx.z;
  int klmax0 = 64*t + 64 + CA; if (klmax0 > S) klmax0 = S;
  int nch = (klmax0 + 63) >> 6;
  int nsp = (nch + 7) >> 3;
  if (sp >= nsp) return;
  int base = 0;
  for (int i = 0; i < t; i++){
    int km = 64*i + 64 + CA; if (km > S) km = S;
    base += (((km + 63) >> 6) + 7) >> 3;
  }
  int pidx = h*TOTS + base + sp;
  // balanced split ranges
  int c0 = sp * nch / nsp;
  int c1 = (sp + 1) * nch / nsp;

  __shared__ __align__(16) unsigned short Ks[2][64*64];   // 16 KB (dbuf)
  __shared__ __align__(16) unsigned short VTs[64*64];     //  8 KB (single)
  __shared__ __align__(16) unsigned short Ps[4][16*72];   // 9.2 KB
  __shared__ float scs[2][64];
  int tid = threadIdx.x;
  int q0 = t*64;
  int w = tid >> 6, lane = tid & 63;
  int cn = lane & 15, quad = lane >> 4, kq = quad * 8;
  unsigned short* Pw = Ps[w];
  int srow0 = w*16;
  int lr = lane >> 3;
  int lc = ((lane & 7) ^ lr) * 8;
  const unsigned short* kg0 = kb + (size_t)(srow0 + lr) * kstride + h*HD + lc;
  const unsigned short* kg1 = kb + (size_t)(srow0 + 8 + lr) * kstride + h*HD + lc;
  const unsigned short* vg0 = vt + (size_t)(h*HD + srow0 + lr) * S + lc;
  const unsigned short* vg1 = vt + (size_t)(h*HD + srow0 + 8 + lr) * S + lc;

  const unsigned short* qrow = qb + (size_t)(q0 + w*16 + cn) * qstride + h*HD;
  short8 qf0 = *(const short8*)(qrow + kq);
  short8 qf1 = *(const short8*)(qrow + kq + 32);
  floatx4 oacc[4] = {};
  float l_lane[4] = {0,0,0,0};
  int qmr = q0 + w*16 + quad*4;

  // prologue: K and scorer for chunk c0 into buffer 0
  {
    int kc = c0 * 64;
    gld16(kg0 + (size_t)kc * kstride, Ks[0] + srow0*64);
    gld16(kg1 + (size_t)kc * kstride, Ks[0] + (srow0 + 8)*64);
    if (SCOR && tid < 64) scs[0][tid] = b2f(scorer[kc + tid]);
  }

  int ib = 0;
  for (int ci = c0; ci < c1; ci++, ib ^= 1){
    int kc = ci * 64;
    __syncthreads();                 // barrier1: prev chunk fully done; K_ci drained
    gld16(vg0 + kc, VTs + srow0*64);
    gld16(vg1 + kc, VTs + (srow0 + 8)*64);
    if (ci + 1 < c1){
      int kn2 = (ci + 1) * 64;
      gld16(kg0 + (size_t)kn2 * kstride, Ks[ib^1] + srow0*64);
      gld16(kg1 + (size_t)kn2 * kstride, Ks[ib^1] + (srow0 + 8)*64);
      if (SCOR && tid < 64) scs[ib^1][tid] = b2f(scorer[kn2 + tid]);
    }
    const unsigned short* Kc = Ks[ib];
    const float* scc = scs[ib];

    floatx4 sv[4] = {};
    #pragma unroll
    for (int t4=0;t4<4;t4++){
      int rr = t4*16 + cn;
      int s0 = ((quad    ) ^ (rr & 7)) * 8;
      int s1 = ((quad + 4) ^ (rr & 7)) * 8;
      short8 b0 = *(const short8*)&Kc[rr*64 + s0];
      short8 b1 = *(const short8*)&Kc[rr*64 + s1];
      sv[t4] = __builtin_amdgcn_mfma_f32_16x16x32_bf16(qf0, b0, sv[t4], 0,0,0);
      sv[t4] = __builtin_amdgcn_mfma_f32_16x16x32_bf16(qf1, b1, sv[t4], 0,0,0);
    }

    if (kc + 63 > q0 + w*16 + CA){          // wave-uniform: diagonal (masked) chunk
      #pragma unroll
      for (int t4=0;t4<4;t4++){
        int kn = kc + t4*16 + cn;
        #pragma unroll
        for (int r=0;r<4;r++){
          float s = sv[t4][r] * SCALE2;
          if (SCOR) s += scc[t4*16 + cn];
          float e = fexp2(s);
          e = (kn <= qmr + r + CA) ? e : 0.f;
          l_lane[r] += e;
          Pw[(quad*4+r)*72 + t4*16 + cn] = f2b(e);
        }
      }
    } else {
      #pragma unroll
      for (int t4=0;t4<4;t4++){
        #pragma unroll
        for (int r=0;r<4;r++){
          float s = sv[t4][r] * SCALE2;
          if (SCOR) s += scc[t4*16 + cn];
          float e = fexp2(s);
          l_lane[r] += e;
          Pw[(quad*4+r)*72 + t4*16 + cn] = f2b(e);
        }
      }
    }
    __syncthreads();                 // barrier2: V_ci visible to all waves
    short8 pf0 = *(const short8*)&Pw[cn*72 + kq];
    short8 pf1 = *(const short8*)&Pw[cn*72 + kq + 32];
    #pragma unroll
    for (int t2=0;t2<4;t2++){
      int rr = t2*16 + cn;
      int s0 = ((quad    ) ^ (rr & 7)) * 8;
      int s1 = ((quad + 4) ^ (rr & 7)) * 8;
      short8 v0 = *(const short8*)&VTs[rr*64 + s0];
      short8 v1 = *(const short8*)&VTs[rr*64 + s1];
      oacc[t2] = __builtin_amdgcn_mfma_f32_16x16x32_bf16(pf0, v0, oacc[t2], 0,0,0);
      oacc[t2] = __builtin_amdgcn_mfma_f32_16x16x32_bf16(pf1, v1, oacc[t2], 0,0,0);
    }
  }

  float lrow[4];
  #pragma unroll
  for (int r=0;r<4;r++){
    float l = l_lane[r];
    l += __shfl_xor(l,1,64); l += __shfl_xor(l,2,64);
    l += __shfl_xor(l,4,64); l += __shfl_xor(l,8,64);
    lrow[r] = l;
  }
  size_t ob = (size_t)pidx*4096 + (size_t)(w*16 + quad*4)*64;
  #pragma unroll
  for (int t2=0;t2<4;t2++){
    #pragma unroll
    for (int r=0;r<4;r++)
      obuf[ob + r*64 + t2*16 + cn] = f2b(oacc[t2][r]);
  }
  if (cn == 0){
    #pragma unroll
    for (int r=0;r<4;r++){
      int row64 = w*16 + quad*4 + r;
      lbuf[(size_t)pidx*64 + row64] = lrow[r];
    }
  }
}

// ---------------- split-K combine (unweighted: m == 0 in all partials) ---------------
template<int CA>
__global__ __launch_bounds__(256) void k_comb(
    const unsigned short* __restrict__ obuf, const float* __restrict__ lbuf,
    unsigned short* __restrict__ out, int TOTS)
{
  int h = blockIdx.y;
  int row = blockIdx.x*16 + (threadIdx.x >> 4);
  int d0 = (threadIdx.x & 15) * 4;
  int t = row >> 6;
  int klmax0 = 64*t + 64 + CA; if (klmax0 > S) klmax0 = S;
  int nch = (klmax0 + 63) >> 6;
  int nsp = (nch + 7) >> 3;
  int base = 0;
  for (int i = 0; i < t; i++){
    int km = 64*i + 64 + CA; if (km > S) km = S;
    base += (((km + 63) >> 6) + 7) >> 3;
  }
  int row64 = row & 63;
  float L = 0.f;
  float o0=0.f,o1=0.f,o2=0.f,o3=0.f;
  for (int p = 0; p < nsp; p++){
    int pi = h*TOTS + base + p;
    L += lbuf[(size_t)pi*64 + row64];
    const unsigned short* op = obuf + (size_t)pi*4096 + row64*64 + d0;
    o0 += b2f(op[0]); o1 += b2f(op[1]);
    o2 += b2f(op[2]); o3 += b2f(op[3]);
  }
  float inv = 1.0f / L;
  size_t oo = (size_t)row*H + h*HD + d0;
  out[oo]   = f2b(o0*inv); out[oo+1] = f2b(o1*inv);
  out[oo+2] = f2b(o2*inv); out[oo+3] = f2b(o3*inv);
}

extern "C" void kernel_launch(void* const* d_in, const int* in_sizes, int n_in,
                              void* d_out, int out_size, void* d_ws, size_t ws_size,
                              hipStream_t stream)
{
  const void* hs          = d_in[0];
  const void* enc         = d_in[1];
  const void* scorer      = d_in[2];
  const void* ln1_g       = d_in[3];
  const void* ln1_b       = d_in[4];
  const void* c_attn_w    = d_in[5];
  const void* c_attn_b    = d_in[6];
  const void* attn_proj_w = d_in[7];
  const void* attn_proj_b = d_in[8];
  const void* lnx_g       = d_in[9];
  const void* lnx_b       = d_in[10];
  const void* q_attn_w    = d_in[11];
  const void* q_attn_b    = d_in[12];
  const void* x_kv_w      = d_in[13];
  const void* x_kv_b      = d_in[14];
  const void* x_proj_w    = d_in[15];
  const void* x_proj_b    = d_in[16];
  const void* ln2_g       = d_in[17];
  const void* ln2_b       = d_in[18];
  const void* fc_w        = d_in[19];
  const void* fc_b        = d_in[20];
  const void* mlp_proj_w  = d_in[21];
  const void* mlp_proj_b  = d_in[22];
  unsigned short* out = (unsigned short*)d_out;

  char* ws = (char*)d_ws; size_t off = 0;
  auto alloc = [&](size_t bytes)->void*{
    void* p = ws + off; off += (bytes + 255) & ~(size_t)255; return p;
  };
  unsigned short* wT_cattn = (unsigned short*)alloc((size_t)3072*1024*2);
  unsigned short* wT_aproj = (unsigned short*)alloc((size_t)1024*1024*2);
  unsigned short* wT_qattn = (unsigned short*)alloc((size_t)1024*1024*2);
  unsigned short* wT_xkv   = (unsigned short*)alloc((size_t)2048*1024*2);
  unsigned short* wT_xproj = (unsigned short*)alloc((size_t)1024*1024*2);
  unsigned short* wT_fc    = (unsigned short*)alloc((size_t)4096*1024*2);
  unsigned short* wT_mlp   = (unsigned short*)alloc((size_t)1024*4096*2);
  unsigned short* enc_c    = (unsigned short*)alloc((size_t)SEQE*H*2);
  unsigned short* canon    = (unsigned short*)alloc((size_t)32768*2);
  unsigned short* xln      = (unsigned short*)alloc((size_t)S*H*2);
  unsigned short* qkv      = (unsigned short*)alloc((size_t)S*3*H*2);
  unsigned short* attnout  = (unsigned short*)alloc((size_t)S*H*2);
  unsigned short* q2       = (unsigned short*)alloc((size_t)S*H*2);
  unsigned short* kvbuf    = (unsigned short*)alloc((size_t)SEQE*2*H*2);
  unsigned short* vt_self  = (unsigned short*)alloc((size_t)H*S*2);
  unsigned short* vt_cross = (unsigned short*)alloc((size_t)H*SEQE*2);
  unsigned short* fcbuf    = (unsigned short*)alloc((size_t)S*INNER*2);
  float*          hidden   = (float*)alloc((size_t)S*H*4);
  int*            flag     = (int*)alloc(256);

  unsigned short* obuf  = fcbuf;
  float*          lbuf  = (float*)(fcbuf + (size_t)16*83*4096);

  unsigned short* p = canon;
  auto carve = [&](int n)->unsigned short*{ unsigned short* q = p; p += n; return q; };
  unsigned short* c_ln1g = carve(1024); unsigned short* c_ln1b = carve(1024);
  unsigned short* c_catb = carve(3072); unsigned short* c_aprb = carve(1024);
  unsigned short* c_lnxg = carve(1024); unsigned short* c_lnxb = carve(1024);
  unsigned short* c_qatb = carve(1024); unsigned short* c_xkvb = carve(2048);
  unsigned short* c_xprb = carve(1024); unsigned short* c_ln2g = carve(1024);
  unsigned short* c_ln2b = carve(1024); unsigned short* c_fcb  = carve(4096);
  unsigned short* c_mlpb = carve(1024); unsigned short* c_scor = carve(2048);

  k_sniff<<<1, 256, 0, stream>>>((const unsigned short*)hs, flag);

  PrepT pt{};
  const void* tsrc[7] = {c_attn_w, attn_proj_w, q_attn_w, x_kv_w, x_proj_w, fc_w, mlp_proj_w};
  unsigned short* tdst[7] = {wT_cattn, wT_aproj, wT_qattn, wT_xkv, wT_xproj, wT_fc, wT_mlp};
  int tR[7] = {1024,1024,1024,1024,1024,1024,4096};
  int tC[7] = {3072,1024,1024,2048,1024,4096,1024};
  int acc_t = 0;
  for (int i=0;i<7;i++){
    pt.src[i]=tsrc[i]; pt.dst[i]=tdst[i]; pt.R[i]=tR[i]; pt.C[i]=tC[i];
    pt.pre[i]=acc_t; acc_t += (tC[i]>>5)*(tR[i]>>5);
  }
  pt.pre[7]=acc_t;
  k_prep_t<<<acc_t, 256, 0, stream>>>(pt, flag);

  SmallCvt sc{};
  const void* ssrc[14] = {ln1_g, ln1_b, c_attn_b, attn_proj_b, lnx_g, lnx_b,
                          q_attn_b, x_kv_b, x_proj_b, ln2_g, ln2_b, fc_b,
                          mlp_proj_b, scorer};
  unsigned short* sdst[14] = {c_ln1g, c_ln1b, c_catb, c_aprb, c_lnxg, c_lnxb,
                              c_qatb, c_xkvb, c_xprb, c_ln2g, c_ln2b, c_fcb,
                              c_mlpb, c_scor};
  int sn[14] = {1024,1024,3072,1024,1024,1024,1024,2048,1024,1024,1024,4096,1024,2048};
  for (int i=0;i<14;i++){ sc.src[i]=ssrc[i]; sc.dst[i]=sdst[i]; sc.n[i]=sn[i]; }
  k_prep_c<<<16384 + 14, 256, 0, stream>>>(enc, enc_c, hs, hidden, sc, flag);

  // --- self attention ---
  k_layernorm<<<S, 256, 0, stream>>>(hidden, c_ln1g, c_ln1b, xln);
  k_gemm64<<<dim3(3072/128, S/64), 256, 0, stream>>>(xln, wT_cattn, c_catb,
      qkv, nullptr, S, 3072, 1024, 4, flag, 2048, vt_self);
  k_flash2<0,0><<<dim3(32, NHEAD, 4), 256, 0, stream>>>(
      qkv, 3*H, qkv + 1024, 3*H, vt_self, nullptr, obuf, lbuf, 80);
  k_comb<0><<<dim3(S/16, NHEAD), 256, 0, stream>>>(obuf, lbuf, attnout, 80);
  k_gemm64s<<<dim3(1024/64, S/64), 256, 0, stream>>>(attnout, wT_aproj, c_aprb,
      nullptr, hidden, S, 1024, 1024, 2, flag);

  // --- cross attention ---
  k_layernorm<<<S, 256, 0, stream>>>(hidden, c_lnxg, c_lnxb, xln);
  k_gemm64s<<<dim3(1024/64, S/64), 256, 0, stream>>>(xln, wT_qattn, c_qatb,
      q2, nullptr, S, 1024, 1024, 0, flag);
  k_gemm64<<<dim3(2048/128, SEQE/64), 256, 0, stream>>>(enc_c, wT_xkv, c_xkvb,
      kvbuf, nullptr, SEQE, 2048, 1024, 4, flag, 1024, vt_cross);
  k_flash2<2,1><<<dim3(32, NHEAD, 4), 256, 0, stream>>>(
      q2, H, kvbuf, 2*H, vt_cross, c_scor, obuf, lbuf, 83);
  k_comb<2><<<dim3(S/16, NHEAD), 256, 0, stream>>>(obuf, lbuf, attnout, 83);
  k_gemm64s<<<dim3(1024/64, S/64), 256, 0, stream>>>(attnout, wT_xproj, c_xprb,
      nullptr, hidden, S, 1024, 1024, 2, flag);

  // --- MLP ---
  k_layernorm<<<S, 256, 0, stream>>>(hidden, c_ln2g, c_ln2b, xln);
  k_gemm64<<<dim3(INNER/128, S/64), 256, 0, stream>>>(xln, wT_fc, c_fcb,
      fcbuf, nullptr, S, INNER, 1024, 1, flag, 0, nullptr);
  k_gemm64s<<<dim3(1024/64, S/64), 256, 0, stream>>>(fcbuf, wT_mlp, c_mlpb,
      out, hidden, S, 1024, INNER, 3, flag);
}